// Round 1
// baseline (266.690 us; speedup 1.0000x reference)
//
#include <hip/hip_runtime.h>

#define GRIDN   16
#define KMAX    32
#define NPER    2048
#define DFEAT   256
#define RCELLS  256     // GRIDN*GRIDN
#define XYS     35      // ints per xy row (3 header + 32 inds)
#define DC      64      // d-columns per block
#define CC      64      // cells per block

__global__ __launch_bounds__(256, 8) void spp_pool_kernel(
    const float* __restrict__ F,     // (B*NPER, DFEAT)
    const int*   __restrict__ xy,    // (B*NPER, XYS)
    float*       __restrict__ out)   // (B, DFEAT, GRIDN, GRIDN)
{
    // blockIdx.x = b*16 + dchunk*4 + cchunk
    int blk    = blockIdx.x;
    int b      = blk >> 4;
    int dchunk = (blk >> 2) & 3;
    int cchunk = blk & 3;
    int d0     = dchunk * DC;
    int c0     = cchunk * CC;

    __shared__ float pooled[CC][DC + 1];   // +1 pad: transpose reads conflict-free
    __shared__ int   pos_l[CC];            // cell -> source row (or -1)
    __shared__ int   cnt_l[CC];

    int tid = threadIdx.x;
    if (tid < CC) pos_l[tid] = -1;
    __syncthreads();

    // Build cell->row map for our 64-cell window; 256 threads scan 256 rows.
    {
        int r = tid;
        const int* xr = xy + ((size_t)b * NPER + (size_t)r) * XYS;
        int row = xr[0];
        if (row >= 0) {
            int cell = row * GRIDN + xr[1];
            if (cell >= c0 && cell < c0 + CC) {
                pos_l[cell - c0] = r;
                cnt_l[cell - c0] = xr[2];
            }
        }
    }
    __syncthreads();

    // Phase A: gather + mean-pool. wave wv handles cells [wv*16, wv*16+16),
    // lane = one of 64 d-columns.
    int wv   = tid >> 6;
    int lane = tid & 63;
    const float* Fb = F + ((size_t)b * NPER) * DFEAT + d0 + lane;

    for (int j = 0; j < CC / 4; ++j) {
        int cl = wv * (CC / 4) + j;
        int r  = pos_l[cl];
        float s   = 0.f;
        float inv = 0.f;
        if (r >= 0) {
            int cnt = cnt_l[cl];
            const int* ip = xy + ((size_t)b * NPER + (size_t)r) * XYS + 3;
            int k = 0;
            for (; k + 4 <= cnt; k += 4) {
                int i0 = ip[k + 0], i1 = ip[k + 1];
                int i2 = ip[k + 2], i3 = ip[k + 3];
                float f0 = Fb[(size_t)i0 * DFEAT];
                float f1 = Fb[(size_t)i1 * DFEAT];
                float f2 = Fb[(size_t)i2 * DFEAT];
                float f3 = Fb[(size_t)i3 * DFEAT];
                s += f0 + f1 + f2 + f3;
            }
            for (; k < cnt; ++k) s += Fb[(size_t)ip[k] * DFEAT];
            inv = 1.f / (float)(cnt > 0 ? cnt : 1);
        }
        pooled[cl][lane] = s * inv;   // banks: (cl*65+lane)%32 -> 2-way, free
    }
    __syncthreads();

    // Phase B: transposed write-out, float4 along cells (contiguous 256B/d-row).
    float* ob = out + (size_t)b * (DFEAT * RCELLS) + (size_t)d0 * RCELLS + c0;
    for (int it = 0; it < 4; ++it) {
        int t = it * 256 + tid;     // 0..1023
        int d = t >> 4;             // 0..63
        int c = (t & 15) * 4;       // 0,4,...,60
        float4 v;
        v.x = pooled[c + 0][d];
        v.y = pooled[c + 1][d];
        v.z = pooled[c + 2][d];
        v.w = pooled[c + 3][d];
        *(float4*)(ob + (size_t)d * RCELLS + c) = v;
    }
}

extern "C" void kernel_launch(void* const* d_in, const int* in_sizes, int n_in,
                              void* d_out, int out_size, void* d_ws, size_t ws_size,
                              hipStream_t stream) {
    const float* F  = (const float*)d_in[0];
    const int*   xy = (const int*)d_in[1];
    float*       out = (float*)d_out;
    int B = in_sizes[2];                 // nodes_per_graph length = 64
    dim3 grid(B * 16), block(256);
    hipLaunchKernelGGL(spp_pool_kernel, grid, block, 0, stream, F, xy, out);
}

// Round 2
// 222.861 us; speedup vs baseline: 1.1967x; 1.1967x over previous
//
#include <hip/hip_runtime.h>

#define GRIDN   16
#define KMAX    32
#define NPER    2048
#define DFEAT   256
#define RCELLS  256     // GRIDN*GRIDN
#define XYS     35      // ints per xy row (3 header + 32 inds)
#define CC      8       // cells per block

__device__ __forceinline__ void add4(float4& a, const float4& b) {
    a.x += b.x; a.y += b.y; a.z += b.z; a.w += b.w;
}

__global__ __launch_bounds__(256, 8) void spp_pool_kernel(
    const float* __restrict__ F,     // (B*NPER, DFEAT)
    const int*   __restrict__ xy,    // (B*NPER, XYS)
    float*       __restrict__ out)   // (B, DFEAT, GRIDN, GRIDN)
{
    // blockIdx.x = b*32 + cchunk   (cchunk covers 8 cells, full D)
    int blk    = blockIdx.x;
    int b      = blk >> 5;
    int c0     = (blk & 31) * CC;

    __shared__ float pooled[CC][DFEAT];     // 8 KB
    __shared__ int   inds_l[CC][KMAX];      // 1 KB
    __shared__ int   pos_l[CC];
    __shared__ int   cnt_l[CC];

    int tid = threadIdx.x;
    if (tid < CC) pos_l[tid] = -1;
    __syncthreads();

    // Stage 1: scan the 256 headers, claim cells in [c0, c0+8).
    {
        int r = tid;   // only first 256 rows carry cells
        const int* xr = xy + ((size_t)b * NPER + (size_t)r) * XYS;
        int row = xr[0];
        if (row >= 0) {
            int cell = row * GRIDN + xr[1];
            if (cell >= c0 && cell < c0 + CC) {
                pos_l[cell - c0] = r;
                cnt_l[cell - c0] = xr[2];
            }
        }
    }
    __syncthreads();

    // Stage 2: cooperatively copy the 8 cells' index lists into LDS.
    {
        int cl = tid >> 5;          // 0..7
        int k  = tid & 31;          // 0..31
        int r  = pos_l[cl];
        inds_l[cl][k] = (r >= 0) ? xy[((size_t)b * NPER + (size_t)r) * XYS + 3 + k] : 0;
    }
    __syncthreads();

    // Stage 3: gather + pool. Wave wv handles cells {wv*2, wv*2+1}.
    // lane l covers floats [4l, 4l+4) of D via float4 -> 1KB per wave-load.
    int wv   = tid >> 6;
    int lane = tid & 63;
    const float4* Fb4 = (const float4*)(F + ((size_t)b * NPER) * DFEAT);

    for (int j = 0; j < 2; ++j) {
        int cl = wv * 2 + j;
        int r  = pos_l[cl];
        float4 acc0 = make_float4(0.f, 0.f, 0.f, 0.f);
        float4 acc1 = make_float4(0.f, 0.f, 0.f, 0.f);
        float inv = 0.f;
        if (r >= 0) {
            int cnt = cnt_l[cl];
            const int* ip = inds_l[cl];
            int k = 0;
            for (; k + 8 <= cnt; k += 8) {
                int i0 = ip[k+0], i1 = ip[k+1], i2 = ip[k+2], i3 = ip[k+3];
                int i4 = ip[k+4], i5 = ip[k+5], i6 = ip[k+6], i7 = ip[k+7];
                float4 f0 = Fb4[(size_t)i0 * 64 + lane];
                float4 f1 = Fb4[(size_t)i1 * 64 + lane];
                float4 f2 = Fb4[(size_t)i2 * 64 + lane];
                float4 f3 = Fb4[(size_t)i3 * 64 + lane];
                float4 f4 = Fb4[(size_t)i4 * 64 + lane];
                float4 f5 = Fb4[(size_t)i5 * 64 + lane];
                float4 f6 = Fb4[(size_t)i6 * 64 + lane];
                float4 f7 = Fb4[(size_t)i7 * 64 + lane];
                add4(acc0, f0); add4(acc1, f1);
                add4(acc0, f2); add4(acc1, f3);
                add4(acc0, f4); add4(acc1, f5);
                add4(acc0, f6); add4(acc1, f7);
            }
            for (; k < cnt; ++k) {
                float4 f = Fb4[(size_t)ip[k] * 64 + lane];
                add4(acc0, f);
            }
            inv = 1.f / (float)(cnt > 0 ? cnt : 1);
        }
        float4 res;
        res.x = (acc0.x + acc1.x) * inv;
        res.y = (acc0.y + acc1.y) * inv;
        res.z = (acc0.z + acc1.z) * inv;
        res.w = (acc0.w + acc1.w) * inv;
        *(float4*)&pooled[cl][lane * 4] = res;
    }
    __syncthreads();

    // Stage 4: transposed write-out. Thread t owns d-row t: 8 cells = 32 B.
    {
        int d = tid;
        float* ob = out + (size_t)b * (DFEAT * RCELLS) + (size_t)d * RCELLS + c0;
        float4 v0, v1;
        v0.x = pooled[0][d]; v0.y = pooled[1][d];
        v0.z = pooled[2][d]; v0.w = pooled[3][d];
        v1.x = pooled[4][d]; v1.y = pooled[5][d];
        v1.z = pooled[6][d]; v1.w = pooled[7][d];
        *(float4*)(ob + 0) = v0;
        *(float4*)(ob + 4) = v1;
    }
}

extern "C" void kernel_launch(void* const* d_in, const int* in_sizes, int n_in,
                              void* d_out, int out_size, void* d_ws, size_t ws_size,
                              hipStream_t stream) {
    const float* F  = (const float*)d_in[0];
    const int*   xy = (const int*)d_in[1];
    float*       out = (float*)d_out;
    int B = in_sizes[2];                 // nodes_per_graph length = 64
    dim3 grid(B * 32), block(256);
    hipLaunchKernelGGL(spp_pool_kernel, grid, block, 0, stream, F, xy, out);
}

// Round 3
// 218.641 us; speedup vs baseline: 1.2198x; 1.0193x over previous
//
#include <hip/hip_runtime.h>

#define GRIDN   16
#define KMAX    32
#define NPER    2048
#define DFEAT   256
#define RCELLS  256     // GRIDN*GRIDN
#define XYS     35      // ints per xy row (3 header + 32 inds)
#define CC      4       // cells per block (1 per wave)

__device__ __forceinline__ void add4(float4& a, const float4& b) {
    a.x += b.x; a.y += b.y; a.z += b.z; a.w += b.w;
}

__global__ __launch_bounds__(256, 8) void spp_pool_kernel(
    const float* __restrict__ F,     // (B*NPER, DFEAT)
    const int*   __restrict__ xy,    // (B*NPER, XYS)
    float*       __restrict__ out,   // (B, DFEAT, GRIDN, GRIDN)
    int B)
{
    // XCD-aware swizzle: HW maps blockIdx%8 -> XCD. Give each XCD B/8 whole
    // batches, dispatched batch-major, so its rolling L2 working set is a few
    // 2MB feature slabs instead of all of them.
    int bx  = blockIdx.x;
    int b, c0;
    if ((B & 7) == 0) {
        int xcd = bx & 7;
        int s   = bx >> 3;                 // per-XCD sequence
        b  = xcd * (B >> 3) + (s >> 6);    // 64 chunks per batch
        c0 = (s & 63) * CC;
    } else {
        b  = bx >> 6;
        c0 = (bx & 63) * CC;
    }

    __shared__ float pooled[CC][DFEAT];   // 4 KB
    __shared__ int   inds_l[CC][KMAX];    // 512 B
    __shared__ int   pos_l[CC];
    __shared__ int   cnt_l[CC];

    int tid = threadIdx.x;
    if (tid < CC) pos_l[tid] = -1;
    __syncthreads();

    // Stage 1: scan 256 headers, claim cells in [c0, c0+CC).
    {
        int r = tid;   // only first 256 rows carry cells
        const int* xr = xy + ((size_t)b * NPER + (size_t)r) * XYS;
        int row = xr[0];
        if (row >= 0) {
            int cl = row * GRIDN + xr[1] - c0;
            if (cl >= 0 && cl < CC) {
                pos_l[cl] = r;
                cnt_l[cl] = xr[2];
            }
        }
    }
    __syncthreads();

    // Stage 2: stage the CC index lists into LDS (coalesced).
    if (tid < CC * KMAX) {
        int cl = tid >> 5;          // 0..CC-1
        int k  = tid & 31;
        int r  = pos_l[cl];
        inds_l[cl][k] = (r >= 0) ? xy[((size_t)b * NPER + (size_t)r) * XYS + 3 + k] : 0;
    }
    __syncthreads();

    // Stage 3: one wave = one cell. lane covers floats [4l,4l+4) of D.
    int wv   = tid >> 6;
    int lane = tid & 63;
    const float4* Fb4 = (const float4*)(F + (size_t)b * NPER * DFEAT);
    {
        int cl = wv;
        int r  = pos_l[cl];
        float4 a0 = make_float4(0.f,0.f,0.f,0.f);
        float4 a1 = make_float4(0.f,0.f,0.f,0.f);
        float inv = 0.f;
        if (r >= 0) {
            int cnt = cnt_l[cl];
            const int* ip = inds_l[cl];
            int k = 0;
            for (; k + 8 <= cnt; k += 8) {
                int i0 = ip[k+0], i1 = ip[k+1], i2 = ip[k+2], i3 = ip[k+3];
                int i4 = ip[k+4], i5 = ip[k+5], i6 = ip[k+6], i7 = ip[k+7];
                float4 f0 = Fb4[(size_t)i0 * 64 + lane];
                float4 f1 = Fb4[(size_t)i1 * 64 + lane];
                float4 f2 = Fb4[(size_t)i2 * 64 + lane];
                float4 f3 = Fb4[(size_t)i3 * 64 + lane];
                float4 f4 = Fb4[(size_t)i4 * 64 + lane];
                float4 f5 = Fb4[(size_t)i5 * 64 + lane];
                float4 f6 = Fb4[(size_t)i6 * 64 + lane];
                float4 f7 = Fb4[(size_t)i7 * 64 + lane];
                add4(a0, f0); add4(a1, f1);
                add4(a0, f2); add4(a1, f3);
                add4(a0, f4); add4(a1, f5);
                add4(a0, f6); add4(a1, f7);
            }
            for (; k < cnt; ++k) {
                add4(a0, Fb4[(size_t)ip[k] * 64 + lane]);
            }
            inv = 1.f / (float)(cnt > 0 ? cnt : 1);
        }
        float4 res;
        res.x = (a0.x + a1.x) * inv;
        res.y = (a0.y + a1.y) * inv;
        res.z = (a0.z + a1.z) * inv;
        res.w = (a0.w + a1.w) * inv;
        *(float4*)&pooled[cl][lane * 4] = res;
    }
    __syncthreads();

    // Stage 4: transposed write-out. Thread d owns one d-row: CC cells = 16 B.
    // Scattered 16B/lane stores; sibling blocks (same XCD) fill the rest of
    // each 64B line -> L2 merges (R1 measured WRITE_SIZE = exact 16 MB).
    {
        int d = tid;
        float4 v;
        v.x = pooled[0][d]; v.y = pooled[1][d];
        v.z = pooled[2][d]; v.w = pooled[3][d];
        *(float4*)(out + (size_t)b * (DFEAT * RCELLS) + (size_t)d * RCELLS + c0) = v;
    }
}

extern "C" void kernel_launch(void* const* d_in, const int* in_sizes, int n_in,
                              void* d_out, int out_size, void* d_ws, size_t ws_size,
                              hipStream_t stream) {
    const float* F  = (const float*)d_in[0];
    const int*   xy = (const int*)d_in[1];
    float*       out = (float*)d_out;
    int B = in_sizes[2];                 // nodes_per_graph length = 64
    dim3 grid(B * (RCELLS / CC)), block(256);
    hipLaunchKernelGGL(spp_pool_kernel, grid, block, 0, stream, F, xy, out, B);
}

// Round 4
// 214.753 us; speedup vs baseline: 1.2418x; 1.0181x over previous
//
#include <hip/hip_runtime.h>

#define GRIDN   16
#define KMAX    32
#define NPER    2048
#define DFEAT   256
#define RCELLS  256     // GRIDN*GRIDN
#define XYS     35      // ints per xy row (3 header + 32 inds)

// ---------------------------------------------------------------------------
// Phase 1: pool each of the first 256 rows per batch into ws[b][cell][d]
// (cell-major => contiguous 1KB store per row; no transpose needed here).
// Block = 256 thr = 4 waves = 2 rows x 2 k-halves. 128 blocks per batch
// => per-XCD resident window ~1 batch => gathers hit L2.
// ---------------------------------------------------------------------------
__global__ __launch_bounds__(256, 4) void spp_pool_phase1(
    const float* __restrict__ F,     // (B*NPER, DFEAT)
    const int*   __restrict__ xy,    // (B*NPER, XYS)
    float*       __restrict__ ws,    // (B, RCELLS, DFEAT)
    int B)
{
    int bx = blockIdx.x;
    int b, chunk;
    if ((B & 7) == 0) {
        // batch-major per XCD: each XCD owns B/8 whole batches
        int xcd = bx & 7;
        int s   = bx >> 3;               // per-XCD sequence
        b     = xcd * (B >> 3) + (s >> 7);
        chunk = s & 127;                 // 128 chunks x 2 rows
    } else {
        b     = bx >> 7;
        chunk = bx & 127;
    }

    int tid  = threadIdx.x;
    int wv   = tid >> 6;     // 0..3
    int lane = tid & 63;
    int rowi = wv >> 1;      // row within block (0..1)
    int kh   = wv & 1;       // k-half (0: k<16, 1: k>=16)
    int r    = chunk * 2 + rowi;

    __shared__ float part[2][DFEAT];    // kh=1 partial sums

    const int* xr = xy + ((size_t)b * NPER + r) * XYS;
    int row = xr[0];
    int col = xr[1];
    int cnt = (row >= 0) ? xr[2] : 0;
    if (cnt > KMAX) cnt = KMAX;
    // lanes 0..15 hold this k-half's indices (coalesced 64B read)
    int vidx = xr[3 + kh * 16 + (lane & 15)];

    const float4* Fb4 = (const float4*)(F + (size_t)b * NPER * DFEAT);
    float4 acc = make_float4(0.f, 0.f, 0.f, 0.f);
    int base = kh * 16;
    #pragma unroll
    for (int rr = 0; rr < 2; ++rr) {
        int kb = base + rr * 8;
        if (kb < cnt) {                  // wave-uniform branch
            int   idx[8];
            float w[8];
            #pragma unroll
            for (int j = 0; j < 8; ++j) {
                int raw = __shfl(vidx, rr * 8 + j);   // v_readlane (uniform)
                bool ok = (kb + j) < cnt;
                idx[j] = ok ? raw : 0;   // masked slots hit row 0 (L1-hot)
                w[j]   = ok ? 1.f : 0.f;
            }
            float4 f[8];
            #pragma unroll
            for (int j = 0; j < 8; ++j)
                f[j] = Fb4[(size_t)idx[j] * 64 + lane];   // 1KB/wave, coalesced
            #pragma unroll
            for (int j = 0; j < 8; ++j) {
                acc.x += w[j] * f[j].x;
                acc.y += w[j] * f[j].y;
                acc.z += w[j] * f[j].z;
                acc.w += w[j] * f[j].w;
            }
        }
    }

    if (kh == 1) *(float4*)&part[rowi][lane * 4] = acc;
    __syncthreads();
    if (kh == 0 && row >= 0) {
        float4 p = *(const float4*)&part[rowi][lane * 4];
        float inv = 1.f / (float)(cnt > 0 ? cnt : 1);
        float4 res;
        res.x = (acc.x + p.x) * inv;
        res.y = (acc.y + p.y) * inv;
        res.z = (acc.z + p.z) * inv;
        res.w = (acc.w + p.w) * inv;
        int cell = row * GRIDN + col;
        *(float4*)(ws + ((size_t)b * RCELLS + cell) * DFEAT + lane * 4) = res;
    }
}

// ---------------------------------------------------------------------------
// Phase 2: transpose ws[b][cell][d] -> out[b][d][cell].
// Block = (b, 64-cell chunk). Thread = one d. Reads coalesced (256B/wave,
// L2/L3-hot, XCD-matched to the phase-1 writer), stores float4-contiguous.
// ---------------------------------------------------------------------------
__global__ __launch_bounds__(256, 4) void spp_pool_phase2(
    const float* __restrict__ ws,
    float*       __restrict__ out,
    int B)
{
    int bx = blockIdx.x;
    int b, c0;
    if ((B & 7) == 0) {
        int xcd = bx & 7;
        int s   = bx >> 3;
        b  = xcd * (B >> 3) + (s >> 2);
        c0 = (s & 3) * 64;
    } else {
        b  = bx >> 2;
        c0 = (bx & 3) * 64;
    }
    int d = threadIdx.x;

    float v[64];
    const float* wsb = ws + (size_t)b * RCELLS * DFEAT + d;
    #pragma unroll
    for (int i = 0; i < 64; ++i)
        v[i] = wsb[(size_t)(c0 + i) * DFEAT];

    float* ob = out + (size_t)b * DFEAT * RCELLS + (size_t)d * RCELLS + c0;
    #pragma unroll
    for (int i = 0; i < 16; ++i) {
        float4 q = make_float4(v[4*i], v[4*i+1], v[4*i+2], v[4*i+3]);
        *(float4*)(ob + 4 * i) = q;
    }
}

extern "C" void kernel_launch(void* const* d_in, const int* in_sizes, int n_in,
                              void* d_out, int out_size, void* d_ws, size_t ws_size,
                              hipStream_t stream) {
    const float* F   = (const float*)d_in[0];
    const int*   xy  = (const int*)d_in[1];
    float*       out = (float*)d_out;
    float*       ws  = (float*)d_ws;      // B*RCELLS*DFEAT*4 = ~16.8 MB
    int B = in_sizes[2];                  // nodes_per_graph length = 64

    hipLaunchKernelGGL(spp_pool_phase1, dim3(B * 128), dim3(256), 0, stream,
                       F, xy, ws, B);
    hipLaunchKernelGGL(spp_pool_phase2, dim3(B * 4), dim3(256), 0, stream,
                       ws, out, B);
}